// Round 4
// baseline (262.796 us; speedup 1.0000x reference)
//
#include <hip/hip_runtime.h>

#define Bsz 256
#define Dd  4096
#define MAXR 15
#define FMAX 3.402823466e+38f
#define KSPLIT 2
#define KCHUNK (Dd / KSPLIT)    // 2048
#define BK 128

typedef short bf16x8 __attribute__((ext_vector_type(8)));
typedef float f32x4  __attribute__((ext_vector_type(4)));

__device__ __forceinline__ unsigned short f2bf(float f) {
    unsigned int u = __float_as_uint(f);
    unsigned int r = (u + 0x7fffu + ((u >> 16) & 1u)) >> 16;   // RNE
    return (unsigned short)r;
}
__device__ __forceinline__ float bf2f(unsigned short h) {
    return __uint_as_float(((unsigned int)h) << 16);
}
// async global->LDS, 16B per lane; LDS dest must be lane-linear (wave base + lane*16)
__device__ __forceinline__ void gld_lds16(const unsigned short* g, unsigned short* l) {
    __builtin_amdgcn_global_load_lds(
        (const __attribute__((address_space(1))) unsigned int*)(const void*)g,
        (__attribute__((address_space(3))) unsigned int*)(void*)l, 16, 0, 0);
}

// ---------------- Kernel 1: x (fp32 binary) -> bf16 (exact) ----------------
__global__ void k_xcvt(const float* __restrict__ x, unsigned short* __restrict__ xb) {
    int i = blockIdx.x * blockDim.x + threadIdx.x;
    xb[i] = f2bf(x[i]);
}

// ------- Kernel 2: S = 0.5*(W + W^T) -> bf16 hi/lo, triangle-paired -------
// block handles tile pair (bi,bj), bi<=bj: reads W tiles (i,j) and (j,i) once,
// writes S tiles at both positions. Reads 67 MB, writes 66 MB (vs 201 MB before).
__global__ __launch_bounds__(256) void k_ssym(const float* __restrict__ W,
                                              unsigned short* __restrict__ shi,
                                              unsigned short* __restrict__ slo) {
    __shared__ float t1[64][68];   // W[i-range][j-range]; pad 68 keeps 16B row align
    __shared__ float t2[64][68];   // W[j-range][i-range]
    int bid = blockIdx.x;
    int bi = 0;
    while (bid >= 64 - bi) { bid -= 64 - bi; ++bi; }
    const int bj = bi + bid;
    const int i0 = bi * 64, j0 = bj * 64;
    const int tid = threadIdx.x;
    const int r  = tid >> 2;            // 0..63
    const int c0 = (tid & 3) * 16;      // 0,16,32,48

    {
        const float* s1 = W + (size_t)(i0 + r) * Dd + j0 + c0;
        const float* s2 = W + (size_t)(j0 + r) * Dd + i0 + c0;
        #pragma unroll
        for (int k = 0; k < 16; k += 4) {
            *(float4*)&t1[r][c0 + k] = *(const float4*)(s1 + k);
            *(float4*)&t2[r][c0 + k] = *(const float4*)(s2 + k);
        }
    }
    __syncthreads();

    // S_ij[r][c] = 0.5*(t1[r][c] + t2[c][r])
    {
        unsigned short vh[16], vl[16];
        #pragma unroll
        for (int k = 0; k < 16; ++k) {
            float s = 0.5f * (t1[r][c0 + k] + t2[c0 + k][r]);
            vh[k] = f2bf(s);
            vl[k] = f2bf(s - bf2f(vh[k]));
        }
        size_t o = (size_t)(i0 + r) * Dd + j0 + c0;
        *(uint4*)(shi + o) = *(const uint4*)&vh[0];
        *(uint4*)(shi + o + 8) = *(const uint4*)&vh[8];
        *(uint4*)(slo + o) = *(const uint4*)&vl[0];
        *(uint4*)(slo + o + 8) = *(const uint4*)&vl[8];
    }
    // S_ji[r][c] = 0.5*(t2[r][c] + t1[c][r])
    if (bi != bj) {
        unsigned short vh[16], vl[16];
        #pragma unroll
        for (int k = 0; k < 16; ++k) {
            float s = 0.5f * (t2[r][c0 + k] + t1[c0 + k][r]);
            vh[k] = f2bf(s);
            vl[k] = f2bf(s - bf2f(vh[k]));
        }
        size_t o = (size_t)(j0 + r) * Dd + i0 + c0;
        *(uint4*)(shi + o) = *(const uint4*)&vh[0];
        *(uint4*)(shi + o + 8) = *(const uint4*)&vh[8];
        *(uint4*)(slo + o) = *(const uint4*)&vl[0];
        *(uint4*)(slo + o + 8) = *(const uint4*)&vl[8];
    }
}

// --------- Kernel 3: partial[z] = X @ S(K-chunk z)  (MFMA bf16 hi/lo) ----------
// grid (64,4,KSPLIT) = 512 blocks -> 2 blocks/CU; BK=128; global_load_lds staging.
__global__ __launch_bounds__(512) void k_gemm(const unsigned short* __restrict__ xb,
                                              const unsigned short* __restrict__ shi,
                                              const unsigned short* __restrict__ slo,
                                              float* __restrict__ part) {
    __shared__ __align__(16) unsigned short As[64 * BK];  // lane-linear, unpadded
    __shared__ __align__(16) unsigned short Bh[64 * BK];
    __shared__ __align__(16) unsigned short Bl[64 * BK];
    const int tid = threadIdx.x;
    const int n0 = blockIdx.x * 64, m0 = blockIdx.y * 64;
    const int kbase = blockIdx.z * KCHUNK;
    const int w = tid >> 6, lane = tid & 63;
    const int wm = w & 3, wn = w >> 2;
    const int ln = lane & 15, quad = lane >> 4;

    // staging: tile = 64 rows x 128 cols bf16 = 16 KB = 1024 slots x 16B; 2 slots/thread
    const int s0 = tid, s1 = tid + 512;
    const size_t ga0 = (size_t)(m0 + (s0 >> 4)) * Dd + (s0 & 15) * 8;
    const size_t ga1 = (size_t)(m0 + (s1 >> 4)) * Dd + (s1 & 15) * 8;
    const size_t gb0 = (size_t)(n0 + (s0 >> 4)) * Dd + (s0 & 15) * 8;
    const size_t gb1 = (size_t)(n0 + (s1 >> 4)) * Dd + (s1 & 15) * 8;

    f32x4 acc[2];
    #pragma unroll
    for (int c = 0; c < 2; ++c)
        #pragma unroll
        for (int r = 0; r < 4; ++r) acc[c][r] = 0.0f;

    for (int k0 = kbase; k0 < kbase + KCHUNK; k0 += BK) {
        __syncthreads();                       // previous compute done before overwrite
        gld_lds16(xb  + ga0 + k0, &As[s0 * 8]);
        gld_lds16(xb  + ga1 + k0, &As[s1 * 8]);
        gld_lds16(shi + gb0 + k0, &Bh[s0 * 8]);
        gld_lds16(shi + gb1 + k0, &Bh[s1 * 8]);
        gld_lds16(slo + gb0 + k0, &Bl[s0 * 8]);
        gld_lds16(slo + gb1 + k0, &Bl[s1 * 8]);
        __syncthreads();                       // vmcnt drain + barrier: LDS tiles ready
        #pragma unroll
        for (int kk = 0; kk < BK; kk += 32) {
            bf16x8 a = *(const bf16x8*)&As[(wm * 16 + ln) * BK + kk + quad * 8];
            #pragma unroll
            for (int c = 0; c < 2; ++c) {
                bf16x8 bh = *(const bf16x8*)&Bh[(wn * 32 + c * 16 + ln) * BK + kk + quad * 8];
                bf16x8 bl = *(const bf16x8*)&Bl[(wn * 32 + c * 16 + ln) * BK + kk + quad * 8];
                acc[c] = __builtin_amdgcn_mfma_f32_16x16x32_bf16(a, bh, acc[c], 0, 0, 0);
                acc[c] = __builtin_amdgcn_mfma_f32_16x16x32_bf16(a, bl, acc[c], 0, 0, 0);
            }
        }
    }
    float* prow = part + (size_t)blockIdx.z * (Bsz * Dd);
    #pragma unroll
    for (int c = 0; c < 2; ++c)
        #pragma unroll
        for (int r = 0; r < 4; ++r) {
            int m = wm * 16 + quad * 4 + r;
            int n = wn * 32 + c * 16 + ln;
            prow[(size_t)(m0 + m) * Dd + n0 + n] = acc[c][r];
        }
}

// --------- Kernel 3b: out = part[0] + part[1] + bias (deterministic order) ---------
__global__ __launch_bounds__(256) void k_reduce(const float* __restrict__ part,
                                                const float* __restrict__ bias,
                                                float* __restrict__ out) {
    int e = (blockIdx.x * 256 + threadIdx.x) * 4;
    float4 a = *(const float4*)(part + e);
    float4 b = *(const float4*)(part + (size_t)Bsz * Dd + e);
    float4 bs = *(const float4*)(bias + (e & (Dd - 1)));
    float4 o;
    o.x = a.x + b.x + bs.x; o.y = a.y + b.y + bs.y;
    o.z = a.z + b.z + bs.z; o.w = a.w + b.w + bs.w;
    *(float4*)(out + e) = o;
}

// ---------------- block reduction helpers (256 threads = 4 waves) ----------------
__device__ __forceinline__ float block_max256(float v, float* redf) {
    #pragma unroll
    for (int off = 32; off; off >>= 1) v = fmaxf(v, __shfl_down(v, off));
    __syncthreads();
    if ((threadIdx.x & 63) == 0) redf[threadIdx.x >> 6] = v;
    __syncthreads();
    return fmaxf(fmaxf(redf[0], redf[1]), fmaxf(redf[2], redf[3]));
}
__device__ __forceinline__ float block_sum256(float v, float* redf) {
    #pragma unroll
    for (int off = 32; off; off >>= 1) v += __shfl_down(v, off);
    __syncthreads();
    if ((threadIdx.x & 63) == 0) redf[threadIdx.x >> 6] = v;
    __syncthreads();
    return (redf[0] + redf[1]) + (redf[2] + redf[3]);    // fixed order: deterministic
}
__device__ __forceinline__ void block_argmax256(float v, int idx, float* redf, int* redi,
                                                float& bv, int& bi) {
    #pragma unroll
    for (int off = 32; off; off >>= 1) {
        float v2 = __shfl_down(v, off);
        int   i2 = __shfl_down(idx, off);
        if (v2 > v || (v2 == v && i2 < idx)) { v = v2; idx = i2; }
    }
    __syncthreads();
    if ((threadIdx.x & 63) == 0) { redf[threadIdx.x >> 6] = v; redi[threadIdx.x >> 6] = idx; }
    __syncthreads();
    bv = redf[0]; bi = redi[0];
    #pragma unroll
    for (int w2 = 1; w2 < 4; ++w2) {
        float v2 = redf[w2]; int i2 = redi[w2];
        if (v2 > bv || (v2 == bv && i2 < bi)) { bv = v2; bi = i2; }
    }
}

// ---------------- Kernel 4: per-row epilogue (block = one sample) ----------------
__global__ __launch_bounds__(256) void k_epilogue(const float* __restrict__ x,
                                                  const float* __restrict__ W,
                                                  const int* __restrict__ radius_raw,
                                                  const float* __restrict__ gu,
                                                  const float* __restrict__ uvec,
                                                  float* __restrict__ out) {
    __shared__ float scx_s[Dd];
    __shared__ float key_s[Dd];
    __shared__ float redf[4];
    __shared__ int   redi[4];
    __shared__ int   flips[MAXR];

    const int b = blockIdx.x;
    const int tid = threadIdx.x;
    const float* grow  = out + (size_t)b * Dd;
    const float* xrow  = x   + (size_t)b * Dd;
    const float* gurow = gu  + (size_t)b * Dd;

    float lmax = -FMAX;
    for (int j = tid; j < Dd; j += 256) {
        float g  = grow[j];
        float xv = xrow[j];
        float sc = (1.0f - 2.0f * xv) * g * 0.5f;
        float uu = fmaxf(gurow[j], 1e-10f);
        float gn = -logf(-logf(uu));
        scx_s[j] = sc;
        key_s[j] = sc + gn;
        lmax = fmaxf(lmax, sc);
    }
    float mx = block_max256(lmax, redf);
    float ls = 0.0f;
    for (int j = tid; j < Dd; j += 256) ls += expf(scx_s[j] - mx);
    float lse_x = mx + logf(block_sum256(ls, redf));

    const int radius = radius_raw[b] + 1;             // [1, 15]
    for (int t = 0; t < radius; ++t) {
        float v = -FMAX; int idx = 0x7fffffff;
        for (int j = tid; j < Dd; j += 256) {
            float kv = key_s[j];
            if (kv > v) { v = kv; idx = j; }
        }
        float bv; int bi;
        block_argmax256(v, idx, redf, redi, bv, bi);
        if (tid == 0) { flips[t] = bi; key_s[bi] = -FMAX; }
        __syncthreads();
    }

    float lmy = -FMAX;
    for (int j = tid; j < Dd; j += 256) {
        float v = scx_s[j];
        for (int t = 0; t < radius; ++t) if (j == flips[t]) v = -v;
        lmy = fmaxf(lmy, v);
    }
    float my = block_max256(lmy, redf);
    float lsy = 0.0f;
    for (int j = tid; j < Dd; j += 256) {
        float v = scx_s[j];
        for (int t = 0; t < radius; ++t) if (j == flips[t]) v = -v;
        lsy += expf(v - my);
    }
    float lse_y = my + logf(block_sum256(lsy, redf));

    float ts = 0.0f;
    for (int t = tid; t < radius * radius; t += 256) {
        int p = flips[t / radius], q = flips[t % radius];
        float dp = 1.0f - 2.0f * xrow[p];
        float dq = 1.0f - 2.0f * xrow[q];
        ts += 0.25f * dp * dq * (W[(size_t)p * Dd + q] + W[(size_t)q * Dd + p]);
    }
    float T = block_sum256(ts, redf);

    float log_acc = fminf(T + lse_x - lse_y, 0.0f);
    int accepted = (expf(log_acc) > uvec[b]) ? 1 : 0;

    __syncthreads();
    float* orow = out + (size_t)b * Dd;
    for (int j = tid; j < Dd; j += 256) orow[j] = xrow[j];
    __syncthreads();
    if (accepted && tid < radius) {
        int p = flips[tid];
        orow[p] = 1.0f - xrow[p];
    }
}

extern "C" void kernel_launch(void* const* d_in, const int* in_sizes, int n_in,
                              void* d_out, int out_size, void* d_ws, size_t ws_size,
                              hipStream_t stream) {
    const float* x          = (const float*)d_in[0];
    const float* W          = (const float*)d_in[1];
    const float* bias       = (const float*)d_in[2];
    const int*   radius_raw = (const int*)d_in[3];
    const float* gu         = (const float*)d_in[4];
    const float* u          = (const float*)d_in[5];
    float* out = (float*)d_out;

    // ws: shi 33.55 MB | slo 33.55 MB | xb 2.1 MB | part 8.39 MB  = 77.6 MB
    unsigned short* shi = (unsigned short*)d_ws;
    unsigned short* slo = shi + (size_t)Dd * Dd;
    unsigned short* xb  = slo + (size_t)Dd * Dd;
    float*          prt = (float*)(xb + (size_t)Bsz * Dd);

    k_xcvt<<<(Bsz * Dd) / 256, 256, 0, stream>>>(x, xb);
    k_ssym<<<2080, 256, 0, stream>>>(W, shi, slo);
    k_gemm<<<dim3(64, 4, KSPLIT), 512, 0, stream>>>(xb, shi, slo, prt);
    k_reduce<<<(Bsz * Dd) / 1024, 256, 0, stream>>>(prt, bias, out);
    k_epilogue<<<Bsz, 256, 0, stream>>>(x, W, radius_raw, gu, u, out);
}

// Round 6
// 203.068 us; speedup vs baseline: 1.2941x; 1.2941x over previous
//
#include <hip/hip_runtime.h>

#define Bsz 256
#define Dd  4096
#define MAXR 15
#define FMAX 3.402823466e+38f
#define KSPLIT 2
#define KCHUNK (Dd / KSPLIT)    // 2048
#define BK 64
#define LSTRIDE 72              // 9 granules (odd): conflict-free phases, 16B-aligned rows

typedef short bf16x8 __attribute__((ext_vector_type(8)));
typedef float f32x4  __attribute__((ext_vector_type(4)));

__device__ __forceinline__ unsigned short f2bf(float f) {
    unsigned int u = __float_as_uint(f);
    unsigned int r = (u + 0x7fffu + ((u >> 16) & 1u)) >> 16;   // RNE
    return (unsigned short)r;
}
__device__ __forceinline__ float bf2f(unsigned short h) {
    return __uint_as_float(((unsigned int)h) << 16);
}

// ---- Kernel 1: S = 0.5*(W+W^T) -> bf16 hi/lo (triangle-paired) + fused x->bf16 ----
// stride 68 floats = 272 B: float4 writes at q*4 B offsets stay 16B-aligned (UB fix).
__global__ __launch_bounds__(256) void k_ssym(const float* __restrict__ W,
                                              const float* __restrict__ x,
                                              unsigned short* __restrict__ shi,
                                              unsigned short* __restrict__ slo,
                                              unsigned short* __restrict__ xb) {
    __shared__ float t1[64][68];
    __shared__ float t2[64][68];
    int bid = blockIdx.x;
    int bi = 0;
    while (bid >= 64 - bi) { bid -= 64 - bi; ++bi; }
    const int bj = bi + bid;
    const int i0 = bi * 64, j0 = bj * 64;
    const int tid = threadIdx.x;

    // coalesced loads: slot s -> row s>>4, float4 q=(s&15)*4 (16B-aligned LDS writes)
    #pragma unroll
    for (int sb = 0; sb < 4; ++sb) {
        int s = sb * 256 + tid;
        int r = s >> 4, q = (s & 15) * 4;
        *(float4*)&t1[r][q] = *(const float4*)(W + (size_t)(i0 + r) * Dd + j0 + q);
        *(float4*)&t2[r][q] = *(const float4*)(W + (size_t)(j0 + r) * Dd + i0 + q);
    }
    __syncthreads();

    const int r = tid >> 2, c0 = (tid & 3) * 16;
    {   // S_ij[r][c] = 0.5*(t1[r][c] + t2[c][r])
        unsigned short vh[16], vl[16];
        #pragma unroll
        for (int k = 0; k < 16; ++k) {
            float s = 0.5f * (t1[r][c0 + k] + t2[c0 + k][r]);
            vh[k] = f2bf(s);
            vl[k] = f2bf(s - bf2f(vh[k]));
        }
        size_t o = (size_t)(i0 + r) * Dd + j0 + c0;
        *(uint4*)(shi + o) = *(const uint4*)&vh[0];
        *(uint4*)(shi + o + 8) = *(const uint4*)&vh[8];
        *(uint4*)(slo + o) = *(const uint4*)&vl[0];
        *(uint4*)(slo + o + 8) = *(const uint4*)&vl[8];
    }
    if (bi != bj) {   // S_ji[r][c] = 0.5*(t2[r][c] + t1[c][r])
        unsigned short vh[16], vl[16];
        #pragma unroll
        for (int k = 0; k < 16; ++k) {
            float s = 0.5f * (t2[r][c0 + k] + t1[c0 + k][r]);
            vh[k] = f2bf(s);
            vl[k] = f2bf(s - bf2f(vh[k]));
        }
        size_t o = (size_t)(j0 + r) * Dd + i0 + c0;
        *(uint4*)(shi + o) = *(const uint4*)&vh[0];
        *(uint4*)(shi + o + 8) = *(const uint4*)&vh[8];
        *(uint4*)(slo + o) = *(const uint4*)&vl[0];
        *(uint4*)(slo + o + 8) = *(const uint4*)&vl[8];
    }

    // fused x (fp32 binary) -> bf16: first 256 blocks convert one 4096-row each
    if (blockIdx.x < 256) {
        const float* xp = x + (size_t)blockIdx.x * 4096;
        unsigned short* xo = xb + (size_t)blockIdx.x * 4096;
        #pragma unroll
        for (int c = 0; c < 4; ++c) {
            int e = c * 1024 + tid * 4;
            float4 v = *(const float4*)(xp + e);
            unsigned short o4[4] = { f2bf(v.x), f2bf(v.y), f2bf(v.z), f2bf(v.w) };
            *(uint2*)(xo + e) = *(const uint2*)o4;
        }
    }
}

// ---- Kernel 2: part[z] = X @ S(K-chunk z); manual staging, stride-72 LDS ----
// grid (64 N, 4 M, KSPLIT); 128 threads = 2 waves; wave tile 64x32 (0.5 reads/MFMA).
__global__ __launch_bounds__(128) void k_gemm(const unsigned short* __restrict__ xb,
                                              const unsigned short* __restrict__ shi,
                                              const unsigned short* __restrict__ slo,
                                              float* __restrict__ part) {
    __shared__ __align__(16) unsigned short As[64 * LSTRIDE];
    __shared__ __align__(16) unsigned short Bh[64 * LSTRIDE];
    __shared__ __align__(16) unsigned short Bl[64 * LSTRIDE];
    const int tid = threadIdx.x;
    const int n0 = blockIdx.x * 64, m0 = blockIdx.y * 64;
    const int kbase = blockIdx.z * KCHUNK;
    const int w = tid >> 6, lane = tid & 63;
    const int ln = lane & 15, quad = lane >> 4;

    // staging map: slot s = tid + j*128 -> row s>>3, granule s&7 (16B each)
    size_t ga[4], gb[4];
    int lofs[4];
    #pragma unroll
    for (int j = 0; j < 4; ++j) {
        int s = tid + j * 128;
        int r = s >> 3, g = s & 7;
        ga[j]   = (size_t)(m0 + r) * Dd + kbase + g * 8;
        gb[j]   = (size_t)(n0 + r) * Dd + kbase + g * 8;
        lofs[j] = r * LSTRIDE + g * 8;
    }

    f32x4 acc[4][2];
    #pragma unroll
    for (int mt = 0; mt < 4; ++mt)
        #pragma unroll
        for (int ct = 0; ct < 2; ++ct)
            #pragma unroll
            for (int rr = 0; rr < 4; ++rr) acc[mt][ct][rr] = 0.0f;

    for (int k0 = 0; k0 < KCHUNK; k0 += BK) {
        __syncthreads();                       // prior compute done before LDS overwrite
        bf16x8 va[4], vh[4], vl[4];
        #pragma unroll
        for (int j = 0; j < 4; ++j) {
            va[j] = *(const bf16x8*)(xb  + ga[j] + k0);
            vh[j] = *(const bf16x8*)(shi + gb[j] + k0);
            vl[j] = *(const bf16x8*)(slo + gb[j] + k0);
        }
        #pragma unroll
        for (int j = 0; j < 4; ++j) {
            *(bf16x8*)&As[lofs[j]] = va[j];
            *(bf16x8*)&Bh[lofs[j]] = vh[j];
            *(bf16x8*)&Bl[lofs[j]] = vl[j];
        }
        __syncthreads();                       // tiles visible to both waves
        #pragma unroll
        for (int kk = 0; kk < BK; kk += 32) {
            const int gr = (kk >> 3) + quad;   // granule 0..7
            bf16x8 a[4];
            #pragma unroll
            for (int mt = 0; mt < 4; ++mt)
                a[mt] = *(const bf16x8*)&As[(mt * 16 + ln) * LSTRIDE + gr * 8];
            #pragma unroll
            for (int ct = 0; ct < 2; ++ct) {
                int rb = w * 32 + ct * 16 + ln;
                bf16x8 bh = *(const bf16x8*)&Bh[rb * LSTRIDE + gr * 8];
                bf16x8 bl = *(const bf16x8*)&Bl[rb * LSTRIDE + gr * 8];
                #pragma unroll
                for (int mt = 0; mt < 4; ++mt) {
                    acc[mt][ct] = __builtin_amdgcn_mfma_f32_16x16x32_bf16(a[mt], bh, acc[mt][ct], 0, 0, 0);
                    acc[mt][ct] = __builtin_amdgcn_mfma_f32_16x16x32_bf16(a[mt], bl, acc[mt][ct], 0, 0, 0);
                }
            }
        }
    }
    float* prow = part + (size_t)blockIdx.z * (Bsz * Dd);
    #pragma unroll
    for (int mt = 0; mt < 4; ++mt)
        #pragma unroll
        for (int ct = 0; ct < 2; ++ct)
            #pragma unroll
            for (int rr = 0; rr < 4; ++rr) {
                int m = m0 + mt * 16 + quad * 4 + rr;
                int n = n0 + w * 32 + ct * 16 + ln;
                prow[(size_t)m * Dd + n] = acc[mt][ct][rr];
            }
}

// ---------------- block reduction helpers (256 threads = 4 waves) ----------------
__device__ __forceinline__ float block_max256(float v, float* redf) {
    #pragma unroll
    for (int off = 32; off; off >>= 1) v = fmaxf(v, __shfl_down(v, off));
    __syncthreads();
    if ((threadIdx.x & 63) == 0) redf[threadIdx.x >> 6] = v;
    __syncthreads();
    return fmaxf(fmaxf(redf[0], redf[1]), fmaxf(redf[2], redf[3]));
}
__device__ __forceinline__ float block_sum256(float v, float* redf) {
    #pragma unroll
    for (int off = 32; off; off >>= 1) v += __shfl_down(v, off);
    __syncthreads();
    if ((threadIdx.x & 63) == 0) redf[threadIdx.x >> 6] = v;
    __syncthreads();
    return (redf[0] + redf[1]) + (redf[2] + redf[3]);    // fixed order: deterministic
}
__device__ __forceinline__ void block_argmax256(float v, int idx, float* redf, int* redi,
                                                float& bv, int& bi) {
    #pragma unroll
    for (int off = 32; off; off >>= 1) {
        float v2 = __shfl_down(v, off);
        int   i2 = __shfl_down(idx, off);
        if (v2 > v || (v2 == v && i2 < idx)) { v = v2; idx = i2; }
    }
    __syncthreads();
    if ((threadIdx.x & 63) == 0) { redf[threadIdx.x >> 6] = v; redi[threadIdx.x >> 6] = idx; }
    __syncthreads();
    bv = redf[0]; bi = redi[0];
    #pragma unroll
    for (int w2 = 1; w2 < 4; ++w2) {
        float v2 = redf[w2]; int i2 = redi[w2];
        if (v2 > bv || (v2 == bv && i2 < bi)) { bv = v2; bi = i2; }
    }
}

// ---- Kernel 3: per-row epilogue; inlines part0+part1+bias reduction ----
__global__ __launch_bounds__(256) void k_epilogue(const float* __restrict__ x,
                                                  const float* __restrict__ W,
                                                  const int* __restrict__ radius_raw,
                                                  const float* __restrict__ gu,
                                                  const float* __restrict__ uvec,
                                                  const float* __restrict__ part,
                                                  const float* __restrict__ bias,
                                                  float* __restrict__ out) {
    __shared__ float scx_s[Dd];
    __shared__ float key_s[Dd];
    __shared__ float redf[4];
    __shared__ int   redi[4];
    __shared__ int   flips[MAXR];

    const int b = blockIdx.x;
    const int tid = threadIdx.x;
    const float* xrow  = x  + (size_t)b * Dd;
    const float* gurow = gu + (size_t)b * Dd;
    const float* p0 = part + (size_t)b * Dd;
    const float* p1 = part + (size_t)(Bsz + b) * Dd;

    // phase 1: grad = (p0+p1)+bias; score_change_x; gumbel keys (vectorized)
    float lmax = -FMAX;
    #pragma unroll
    for (int c = 0; c < 4; ++c) {
        int j = c * 1024 + tid * 4;
        float4 a0 = *(const float4*)(p0 + j);
        float4 a1 = *(const float4*)(p1 + j);
        float4 bs = *(const float4*)(bias + j);
        float4 xv = *(const float4*)(xrow + j);
        float4 uu = *(const float4*)(gurow + j);
        float g0 = a0.x + a1.x + bs.x, g1 = a0.y + a1.y + bs.y;
        float g2 = a0.z + a1.z + bs.z, g3 = a0.w + a1.w + bs.w;
        float4 sc, ky;
        sc.x = (1.0f - 2.0f * xv.x) * g0 * 0.5f;
        sc.y = (1.0f - 2.0f * xv.y) * g1 * 0.5f;
        sc.z = (1.0f - 2.0f * xv.z) * g2 * 0.5f;
        sc.w = (1.0f - 2.0f * xv.w) * g3 * 0.5f;
        ky.x = sc.x - logf(-logf(fmaxf(uu.x, 1e-10f)));
        ky.y = sc.y - logf(-logf(fmaxf(uu.y, 1e-10f)));
        ky.z = sc.z - logf(-logf(fmaxf(uu.z, 1e-10f)));
        ky.w = sc.w - logf(-logf(fmaxf(uu.w, 1e-10f)));
        *(float4*)&scx_s[j] = sc;
        *(float4*)&key_s[j] = ky;
        lmax = fmaxf(lmax, fmaxf(fmaxf(sc.x, sc.y), fmaxf(sc.z, sc.w)));
    }
    float mx = block_max256(lmax, redf);
    float ls = 0.0f;
    for (int j = tid; j < Dd; j += 256) ls += expf(scx_s[j] - mx);
    float lse_x = mx + logf(block_sum256(ls, redf));

    // top-radius via sequential block argmax (tie -> lowest index, matches top_k)
    const int radius = radius_raw[b] + 1;             // [1, 15]
    for (int t = 0; t < radius; ++t) {
        float v = -FMAX; int idx = 0x7fffffff;
        for (int j = tid; j < Dd; j += 256) {
            float kv = key_s[j];
            if (kv > v) { v = kv; idx = j; }
        }
        float bv; int bi;
        block_argmax256(v, idx, redf, redi, bv, bi);
        if (tid == 0) { flips[t] = bi; key_s[bi] = -FMAX; }
        __syncthreads();
    }

    // lse_y: scx sign-flipped at flip positions
    float lmy = -FMAX;
    for (int j = tid; j < Dd; j += 256) {
        float v = scx_s[j];
        for (int t = 0; t < radius; ++t) if (j == flips[t]) v = -v;
        lmy = fmaxf(lmy, v);
    }
    float my = block_max256(lmy, redf);
    float lsy = 0.0f;
    for (int j = tid; j < Dd; j += 256) {
        float v = scx_s[j];
        for (int t = 0; t < radius; ++t) if (j == flips[t]) v = -v;
        lsy += expf(v - my);
    }
    float lse_y = my + logf(block_sum256(lsy, redf));

    // pair term: 0.25 * sum_{p,q in flips} d_p d_q (W_pq + W_qp)
    float ts = 0.0f;
    for (int t = tid; t < radius * radius; t += 256) {
        int p = flips[t / radius], q = flips[t % radius];
        float dp = 1.0f - 2.0f * xrow[p];
        float dq = 1.0f - 2.0f * xrow[q];
        ts += 0.25f * dp * dq * (W[(size_t)p * Dd + q] + W[(size_t)q * Dd + p]);
    }
    float T = block_sum256(ts, redf);

    float log_acc = fminf(T + lse_x - lse_y, 0.0f);
    int accepted = (expf(log_acc) > uvec[b]) ? 1 : 0;

    __syncthreads();
    float* orow = out + (size_t)b * Dd;
    #pragma unroll
    for (int c = 0; c < 4; ++c) {
        int j = c * 1024 + tid * 4;
        *(float4*)(orow + j) = *(const float4*)(xrow + j);
    }
    __syncthreads();
    if (accepted && tid < radius) {
        int p = flips[tid];
        orow[p] = 1.0f - xrow[p];
    }
}

extern "C" void kernel_launch(void* const* d_in, const int* in_sizes, int n_in,
                              void* d_out, int out_size, void* d_ws, size_t ws_size,
                              hipStream_t stream) {
    const float* x          = (const float*)d_in[0];
    const float* W          = (const float*)d_in[1];
    const float* bias       = (const float*)d_in[2];
    const int*   radius_raw = (const int*)d_in[3];
    const float* gu         = (const float*)d_in[4];
    const float* u          = (const float*)d_in[5];
    float* out = (float*)d_out;

    // ws: shi 33.55 MB | slo 33.55 MB | xb 2.1 MB | part 8.39 MB = 77.6 MB (proven fit)
    unsigned short* shi = (unsigned short*)d_ws;
    unsigned short* slo = shi + (size_t)Dd * Dd;
    unsigned short* xb  = slo + (size_t)Dd * Dd;
    float*          prt = (float*)(xb + (size_t)Bsz * Dd);

    k_ssym<<<2080, 256, 0, stream>>>(W, x, shi, slo, xb);
    k_gemm<<<dim3(64, 4, KSPLIT), 128, 0, stream>>>(xb, shi, slo, prt);
    k_epilogue<<<Bsz, 256, 0, stream>>>(x, W, radius_raw, gu, u, prt, bias, out);
}

// Round 7
// 180.889 us; speedup vs baseline: 1.4528x; 1.1226x over previous
//
#include <hip/hip_runtime.h>

#define Bsz 256
#define Dd  4096
#define MAXR 15
#define FMAX 3.402823466e+38f
#define KSPLIT 2
#define KCHUNK (Dd / KSPLIT)    // 2048
#define BK 64
#define LSTRIDE 72              // 9 granules (odd): conflict-free phases, 16B-aligned rows

typedef short bf16x8 __attribute__((ext_vector_type(8)));
typedef float f32x4  __attribute__((ext_vector_type(4)));

__device__ __forceinline__ unsigned short f2bf(float f) {
    unsigned int u = __float_as_uint(f);
    unsigned int r = (u + 0x7fffu + ((u >> 16) & 1u)) >> 16;   // RNE
    return (unsigned short)r;
}
__device__ __forceinline__ float bf2f(unsigned short h) {
    return __uint_as_float(((unsigned int)h) << 16);
}

// ---- Kernel 1: S = 0.5*(W+W^T) -> bf16 hi/lo (triangle-paired) + fused x->bf16 ----
__global__ __launch_bounds__(256) void k_ssym(const float* __restrict__ W,
                                              const float* __restrict__ x,
                                              unsigned short* __restrict__ shi,
                                              unsigned short* __restrict__ slo,
                                              unsigned short* __restrict__ xb) {
    __shared__ float t1[64][68];
    __shared__ float t2[64][68];
    int bid = blockIdx.x;
    int bi = 0;
    while (bid >= 64 - bi) { bid -= 64 - bi; ++bi; }
    const int bj = bi + bid;
    const int i0 = bi * 64, j0 = bj * 64;
    const int tid = threadIdx.x;

    #pragma unroll
    for (int sb = 0; sb < 4; ++sb) {
        int s = sb * 256 + tid;
        int r = s >> 4, q = (s & 15) * 4;
        *(float4*)&t1[r][q] = *(const float4*)(W + (size_t)(i0 + r) * Dd + j0 + q);
        *(float4*)&t2[r][q] = *(const float4*)(W + (size_t)(j0 + r) * Dd + i0 + q);
    }
    __syncthreads();

    const int r = tid >> 2, c0 = (tid & 3) * 16;
    {   // S_ij[r][c] = 0.5*(t1[r][c] + t2[c][r])
        unsigned short vh[16], vl[16];
        #pragma unroll
        for (int k = 0; k < 16; ++k) {
            float s = 0.5f * (t1[r][c0 + k] + t2[c0 + k][r]);
            vh[k] = f2bf(s);
            vl[k] = f2bf(s - bf2f(vh[k]));
        }
        size_t o = (size_t)(i0 + r) * Dd + j0 + c0;
        *(uint4*)(shi + o) = *(const uint4*)&vh[0];
        *(uint4*)(shi + o + 8) = *(const uint4*)&vh[8];
        *(uint4*)(slo + o) = *(const uint4*)&vl[0];
        *(uint4*)(slo + o + 8) = *(const uint4*)&vl[8];
    }
    if (bi != bj) {   // S_ji[r][c] = 0.5*(t2[r][c] + t1[c][r])
        unsigned short vh[16], vl[16];
        #pragma unroll
        for (int k = 0; k < 16; ++k) {
            float s = 0.5f * (t2[r][c0 + k] + t1[c0 + k][r]);
            vh[k] = f2bf(s);
            vl[k] = f2bf(s - bf2f(vh[k]));
        }
        size_t o = (size_t)(j0 + r) * Dd + i0 + c0;
        *(uint4*)(shi + o) = *(const uint4*)&vh[0];
        *(uint4*)(shi + o + 8) = *(const uint4*)&vh[8];
        *(uint4*)(slo + o) = *(const uint4*)&vl[0];
        *(uint4*)(slo + o + 8) = *(const uint4*)&vl[8];
    }

    if (blockIdx.x < 256) {
        const float* xp = x + (size_t)blockIdx.x * 4096;
        unsigned short* xo = xb + (size_t)blockIdx.x * 4096;
        #pragma unroll
        for (int c = 0; c < 4; ++c) {
            int e = c * 1024 + tid * 4;
            float4 v = *(const float4*)(xp + e);
            unsigned short o4[4] = { f2bf(v.x), f2bf(v.y), f2bf(v.z), f2bf(v.w) };
            *(uint2*)(xo + e) = *(const uint2*)o4;
        }
    }
}

// ---- Kernel 2: part[z] = X @ S(K-chunk z); manual staging, stride-72 LDS ----
__global__ __launch_bounds__(128) void k_gemm(const unsigned short* __restrict__ xb,
                                              const unsigned short* __restrict__ shi,
                                              const unsigned short* __restrict__ slo,
                                              float* __restrict__ part) {
    __shared__ __align__(16) unsigned short As[64 * LSTRIDE];
    __shared__ __align__(16) unsigned short Bh[64 * LSTRIDE];
    __shared__ __align__(16) unsigned short Bl[64 * LSTRIDE];
    const int tid = threadIdx.x;
    const int n0 = blockIdx.x * 64, m0 = blockIdx.y * 64;
    const int kbase = blockIdx.z * KCHUNK;
    const int w = tid >> 6, lane = tid & 63;
    const int ln = lane & 15, quad = lane >> 4;

    size_t ga[4], gb[4];
    int lofs[4];
    #pragma unroll
    for (int j = 0; j < 4; ++j) {
        int s = tid + j * 128;
        int r = s >> 3, g = s & 7;
        ga[j]   = (size_t)(m0 + r) * Dd + kbase + g * 8;
        gb[j]   = (size_t)(n0 + r) * Dd + kbase + g * 8;
        lofs[j] = r * LSTRIDE + g * 8;
    }

    f32x4 acc[4][2];
    #pragma unroll
    for (int mt = 0; mt < 4; ++mt)
        #pragma unroll
        for (int ct = 0; ct < 2; ++ct)
            #pragma unroll
            for (int rr = 0; rr < 4; ++rr) acc[mt][ct][rr] = 0.0f;

    for (int k0 = 0; k0 < KCHUNK; k0 += BK) {
        __syncthreads();
        bf16x8 va[4], vh[4], vl[4];
        #pragma unroll
        for (int j = 0; j < 4; ++j) {
            va[j] = *(const bf16x8*)(xb  + ga[j] + k0);
            vh[j] = *(const bf16x8*)(shi + gb[j] + k0);
            vl[j] = *(const bf16x8*)(slo + gb[j] + k0);
        }
        #pragma unroll
        for (int j = 0; j < 4; ++j) {
            *(bf16x8*)&As[lofs[j]] = va[j];
            *(bf16x8*)&Bh[lofs[j]] = vh[j];
            *(bf16x8*)&Bl[lofs[j]] = vl[j];
        }
        __syncthreads();
        #pragma unroll
        for (int kk = 0; kk < BK; kk += 32) {
            const int gr = (kk >> 3) + quad;
            bf16x8 a[4];
            #pragma unroll
            for (int mt = 0; mt < 4; ++mt)
                a[mt] = *(const bf16x8*)&As[(mt * 16 + ln) * LSTRIDE + gr * 8];
            #pragma unroll
            for (int ct = 0; ct < 2; ++ct) {
                int rb = w * 32 + ct * 16 + ln;
                bf16x8 bh = *(const bf16x8*)&Bh[rb * LSTRIDE + gr * 8];
                bf16x8 bl = *(const bf16x8*)&Bl[rb * LSTRIDE + gr * 8];
                #pragma unroll
                for (int mt = 0; mt < 4; ++mt) {
                    acc[mt][ct] = __builtin_amdgcn_mfma_f32_16x16x32_bf16(a[mt], bh, acc[mt][ct], 0, 0, 0);
                    acc[mt][ct] = __builtin_amdgcn_mfma_f32_16x16x32_bf16(a[mt], bl, acc[mt][ct], 0, 0, 0);
                }
            }
        }
    }
    float* prow = part + (size_t)blockIdx.z * (Bsz * Dd);
    #pragma unroll
    for (int mt = 0; mt < 4; ++mt)
        #pragma unroll
        for (int ct = 0; ct < 2; ++ct)
            #pragma unroll
            for (int rr = 0; rr < 4; ++rr) {
                int m = m0 + mt * 16 + quad * 4 + rr;
                int n = n0 + w * 32 + ct * 16 + ln;
                prow[(size_t)m * Dd + n] = acc[mt][ct][rr];
            }
}

// ---------------- block reduction helpers (256 threads = 4 waves) ----------------
__device__ __forceinline__ float block_max256(float v, float* redf) {
    #pragma unroll
    for (int off = 32; off; off >>= 1) v = fmaxf(v, __shfl_down(v, off));
    __syncthreads();
    if ((threadIdx.x & 63) == 0) redf[threadIdx.x >> 6] = v;
    __syncthreads();
    return fmaxf(fmaxf(redf[0], redf[1]), fmaxf(redf[2], redf[3]));
}
__device__ __forceinline__ float block_sum256(float v, float* redf) {
    #pragma unroll
    for (int off = 32; off; off >>= 1) v += __shfl_down(v, off);
    __syncthreads();
    if ((threadIdx.x & 63) == 0) redf[threadIdx.x >> 6] = v;
    __syncthreads();
    return (redf[0] + redf[1]) + (redf[2] + redf[3]);    // fixed order: deterministic
}

// ---- Kernel 3: per-row epilogue; register-cached top-k + algebraic lse_y ----
__global__ __launch_bounds__(256) void k_epilogue(const float* __restrict__ x,
                                                  const float* __restrict__ W,
                                                  const int* __restrict__ radius_raw,
                                                  const float* __restrict__ gu,
                                                  const float* __restrict__ uvec,
                                                  const float* __restrict__ part,
                                                  const float* __restrict__ bias,
                                                  float* __restrict__ out) {
    __shared__ float scx_s[Dd];        // 16 KB: sc values for flip-position lookups
    __shared__ float redf[2][4];       // double-buffered argmax combine
    __shared__ int   redi[2][4];
    __shared__ float redsum[4];
    __shared__ int   flips[MAXR];

    const int b = blockIdx.x;
    const int tid = threadIdx.x;
    const float* xrow  = x  + (size_t)b * Dd;
    const float* gurow = gu + (size_t)b * Dd;
    const float* p0 = part + (size_t)b * Dd;
    const float* p1 = part + (size_t)(Bsz + b) * Dd;

    // ---- phase 1: load all streams, compute sc[16], key[16] in registers ----
    // element j = c*1024 + tid*4 + e  (owner(j) = (j>>2)&255, reg = (j>>10)*4 + (j&3))
    float4 a0[4], a1[4], bs4[4], xv4[4], uu4[4];
    #pragma unroll
    for (int c = 0; c < 4; ++c) {
        int j = c * 1024 + tid * 4;
        a0[c]  = *(const float4*)(p0 + j);
        a1[c]  = *(const float4*)(p1 + j);
        bs4[c] = *(const float4*)(bias + j);
        xv4[c] = *(const float4*)(xrow + j);
        uu4[c] = *(const float4*)(gurow + j);
    }
    float sc[16], ky[16];
    float lmax = -FMAX;
    float lkey = -FMAX; int lidx = 0x7fffffff;
    #pragma unroll
    for (int c = 0; c < 4; ++c) {
        const float* ga = (const float*)&a0[c];
        const float* gb = (const float*)&a1[c];
        const float* gc = (const float*)&bs4[c];
        const float* gx = (const float*)&xv4[c];
        const float* gup = (const float*)&uu4[c];
        #pragma unroll
        for (int e = 0; e < 4; ++e) {
            int r = c * 4 + e;
            float g = ga[e] + gb[e] + gc[e];
            float s = (1.0f - 2.0f * gx[e]) * g * 0.5f;
            float k = s - logf(-logf(fmaxf(gup[e], 1e-10f)));
            sc[r] = s;
            ky[r] = k;
            lmax = fmaxf(lmax, s);
            if (k > lkey) { lkey = k; lidx = c * 1024 + tid * 4 + e; }  // incr j: lowest-idx tie
        }
        *(float4*)&scx_s[c * 1024 + tid * 4] = *(const float4*)&sc[c * 4];
    }

    // ---- lse_x ----
    float mx = block_max256(lmax, redsum);
    float ls = 0.0f;
    #pragma unroll
    for (int r = 0; r < 16; ++r) ls += expf(sc[r] - mx);
    float sum_x = block_sum256(ls, redsum);
    float lse_x = mx + logf(sum_x);

    // ---- top-radius: tournament over register-cached per-thread maxima ----
    const int radius = radius_raw[b] + 1;             // [1, 15]
    unsigned removed = 0;
    for (int t = 0; t < radius; ++t) {
        float v = lkey; int idx = lidx;
        #pragma unroll
        for (int off = 32; off; off >>= 1) {
            float v2 = __shfl_down(v, off);
            int   i2 = __shfl_down(idx, off);
            if (v2 > v || (v2 == v && i2 < idx)) { v = v2; idx = i2; }
        }
        const int buf = t & 1;
        if ((tid & 63) == 0) { redf[buf][tid >> 6] = v; redi[buf][tid >> 6] = idx; }
        __syncthreads();
        float bv = redf[buf][0]; int bi = redi[buf][0];
        #pragma unroll
        for (int w2 = 1; w2 < 4; ++w2) {
            float v2 = redf[buf][w2]; int i2 = redi[buf][w2];
            if (v2 > bv || (v2 == bv && i2 < bi)) { bv = v2; bi = i2; }
        }
        if (tid == ((bi >> 2) & 255)) {       // owner: remove + rescan registers
            removed |= 1u << (((bi >> 10) << 2) | (bi & 3));
            lkey = -FMAX; lidx = 0x7fffffff;
            #pragma unroll
            for (int c = 0; c < 4; ++c)
                #pragma unroll
                for (int e = 0; e < 4; ++e) {
                    int r = c * 4 + e;
                    if (!(removed & (1u << r)) && ky[r] > lkey) {
                        lkey = ky[r]; lidx = c * 1024 + tid * 4 + e;
                    }
                }
        }
        if (tid == 0) flips[t] = bi;
    }
    __syncthreads();                           // flips[] visible to all

    // ---- lse_y via correction: sum_y = sum_x + sum_flips(e^{-sc-mx} - e^{+sc-mx}) ----
    float delta = 0.0f;
    if (tid < radius) {
        float sv = scx_s[flips[tid]];
        delta = expf(-sv - mx) - expf(sv - mx);
    }
    float sum_y = sum_x + block_sum256(delta, redsum);
    float lse_y = mx + logf(sum_y);

    // ---- pair term: 0.25 * sum_{p,q in flips} d_p d_q (W_pq + W_qp) ----
    float ts = 0.0f;
    for (int t = tid; t < radius * radius; t += 256) {
        int p = flips[t / radius], q = flips[t % radius];
        float dp = 1.0f - 2.0f * xrow[p];
        float dq = 1.0f - 2.0f * xrow[q];
        ts += 0.25f * dp * dq * (W[(size_t)p * Dd + q] + W[(size_t)q * Dd + p]);
    }
    float T = block_sum256(ts, redsum);

    float log_acc = fminf(T + lse_x - lse_y, 0.0f);
    int accepted = (expf(log_acc) > uvec[b]) ? 1 : 0;

    // ---- output: x everywhere (from registers), flips overwritten iff accepted ----
    float* orow = out + (size_t)b * Dd;
    #pragma unroll
    for (int c = 0; c < 4; ++c)
        *(float4*)(orow + c * 1024 + tid * 4) = xv4[c];
    __syncthreads();
    if (accepted && tid < radius) {
        int p = flips[tid];
        orow[p] = 1.0f - xrow[p];
    }
}

extern "C" void kernel_launch(void* const* d_in, const int* in_sizes, int n_in,
                              void* d_out, int out_size, void* d_ws, size_t ws_size,
                              hipStream_t stream) {
    const float* x          = (const float*)d_in[0];
    const float* W          = (const float*)d_in[1];
    const float* bias       = (const float*)d_in[2];
    const int*   radius_raw = (const int*)d_in[3];
    const float* gu         = (const float*)d_in[4];
    const float* u          = (const float*)d_in[5];
    float* out = (float*)d_out;

    // ws: shi 33.55 MB | slo 33.55 MB | xb 2.1 MB | part 8.39 MB = 77.6 MB (proven fit)
    unsigned short* shi = (unsigned short*)d_ws;
    unsigned short* slo = shi + (size_t)Dd * Dd;
    unsigned short* xb  = slo + (size_t)Dd * Dd;
    float*          prt = (float*)(xb + (size_t)Bsz * Dd);

    k_ssym<<<2080, 256, 0, stream>>>(W, x, shi, slo, xb);
    k_gemm<<<dim3(64, 4, KSPLIT), 128, 0, stream>>>(xb, shi, slo, prt);
    k_epilogue<<<Bsz, 256, 0, stream>>>(x, W, radius_raw, gu, u, prt, bias, out);
}

// Round 8
// 174.049 us; speedup vs baseline: 1.5099x; 1.0393x over previous
//
#include <hip/hip_runtime.h>

#define Bsz 256
#define Dd  4096
#define MAXR 15
#define FMAX 3.402823466e+38f
#define BK 64
#define LSTRIDE 72              // 9 granules (odd): conflict-free phases, 16B-aligned rows

typedef short bf16x8 __attribute__((ext_vector_type(8)));
typedef float f32x4  __attribute__((ext_vector_type(4)));

__device__ __forceinline__ unsigned short f2bf(float f) {
    unsigned int u = __float_as_uint(f);
    unsigned int r = (u + 0x7fffu + ((u >> 16) & 1u)) >> 16;   // RNE
    return (unsigned short)r;
}
__device__ __forceinline__ float bf2f(unsigned short h) {
    return __uint_as_float(((unsigned int)h) << 16);
}

// ---- Kernel 1: S = 0.5*(W+W^T) -> bf16 hi/lo (triangle-paired) + fused x->bf16 ----
__global__ __launch_bounds__(256) void k_ssym(const float* __restrict__ W,
                                              const float* __restrict__ x,
                                              unsigned short* __restrict__ shi,
                                              unsigned short* __restrict__ slo,
                                              unsigned short* __restrict__ xb) {
    __shared__ float t1[64][68];
    __shared__ float t2[64][68];
    int bid = blockIdx.x;
    int bi = 0;
    while (bid >= 64 - bi) { bid -= 64 - bi; ++bi; }
    const int bj = bi + bid;
    const int i0 = bi * 64, j0 = bj * 64;
    const int tid = threadIdx.x;

    #pragma unroll
    for (int sb = 0; sb < 4; ++sb) {
        int s = sb * 256 + tid;
        int r = s >> 4, q = (s & 15) * 4;
        *(float4*)&t1[r][q] = *(const float4*)(W + (size_t)(i0 + r) * Dd + j0 + q);
        *(float4*)&t2[r][q] = *(const float4*)(W + (size_t)(j0 + r) * Dd + i0 + q);
    }
    __syncthreads();

    const int r = tid >> 2, c0 = (tid & 3) * 16;
    {   // S_ij[r][c] = 0.5*(t1[r][c] + t2[c][r])
        unsigned short vh[16], vl[16];
        #pragma unroll
        for (int k = 0; k < 16; ++k) {
            float s = 0.5f * (t1[r][c0 + k] + t2[c0 + k][r]);
            vh[k] = f2bf(s);
            vl[k] = f2bf(s - bf2f(vh[k]));
        }
        size_t o = (size_t)(i0 + r) * Dd + j0 + c0;
        *(uint4*)(shi + o) = *(const uint4*)&vh[0];
        *(uint4*)(shi + o + 8) = *(const uint4*)&vh[8];
        *(uint4*)(slo + o) = *(const uint4*)&vl[0];
        *(uint4*)(slo + o + 8) = *(const uint4*)&vl[8];
    }
    if (bi != bj) {   // S_ji[r][c] = 0.5*(t2[r][c] + t1[c][r])
        unsigned short vh[16], vl[16];
        #pragma unroll
        for (int k = 0; k < 16; ++k) {
            float s = 0.5f * (t2[r][c0 + k] + t1[c0 + k][r]);
            vh[k] = f2bf(s);
            vl[k] = f2bf(s - bf2f(vh[k]));
        }
        size_t o = (size_t)(j0 + r) * Dd + i0 + c0;
        *(uint4*)(shi + o) = *(const uint4*)&vh[0];
        *(uint4*)(shi + o + 8) = *(const uint4*)&vh[8];
        *(uint4*)(slo + o) = *(const uint4*)&vl[0];
        *(uint4*)(slo + o + 8) = *(const uint4*)&vl[8];
    }

    if (blockIdx.x < 256) {
        const float* xp = x + (size_t)blockIdx.x * 4096;
        unsigned short* xo = xb + (size_t)blockIdx.x * 4096;
        #pragma unroll
        for (int c = 0; c < 4; ++c) {
            int e = c * 1024 + tid * 4;
            float4 v = *(const float4*)(xp + e);
            unsigned short o4[4] = { f2bf(v.x), f2bf(v.y), f2bf(v.z), f2bf(v.w) };
            *(uint2*)(xo + e) = *(const uint2*)o4;
        }
    }
}

// ---- Kernel 2: part[z] = X @ S(K-chunk z); VGPR-prefetch pipeline ----
// grid (64 N, 4 M, nsplit); 128 threads = 2 waves; wave tile 64x32 (0.5 reads/MFMA).
// Pipeline: barrier; ds_write(cur); issue global loads(next); barrier; compute(cur).
__global__ __launch_bounds__(128) void k_gemm(const unsigned short* __restrict__ xb,
                                              const unsigned short* __restrict__ shi,
                                              const unsigned short* __restrict__ slo,
                                              float* __restrict__ part,
                                              int kchunk) {
    __shared__ __align__(16) unsigned short As[64 * LSTRIDE];
    __shared__ __align__(16) unsigned short Bh[64 * LSTRIDE];
    __shared__ __align__(16) unsigned short Bl[64 * LSTRIDE];
    const int tid = threadIdx.x;
    const int n0 = blockIdx.x * 64, m0 = blockIdx.y * 64;
    const int kbase = blockIdx.z * kchunk;
    const int w = tid >> 6, lane = tid & 63;
    const int ln = lane & 15, quad = lane >> 4;

    unsigned ga[4], gb[4];
    int lofs[4];
    #pragma unroll
    for (int j = 0; j < 4; ++j) {
        int s = tid + j * 128;
        int r = s >> 3, g = s & 7;
        ga[j]   = (unsigned)((m0 + r) * Dd + kbase + g * 8);
        gb[j]   = (unsigned)((n0 + r) * Dd + kbase + g * 8);
        lofs[j] = r * LSTRIDE + g * 8;
    }

    f32x4 acc[4][2];
    #pragma unroll
    for (int mt = 0; mt < 4; ++mt)
        #pragma unroll
        for (int ct = 0; ct < 2; ++ct)
            #pragma unroll
            for (int rr = 0; rr < 4; ++rr) acc[mt][ct][rr] = 0.0f;

    // preload iteration 0 into registers
    bf16x8 va[4], vh[4], vl[4];
    #pragma unroll
    for (int j = 0; j < 4; ++j) {
        va[j] = *(const bf16x8*)(xb  + ga[j]);
        vh[j] = *(const bf16x8*)(shi + gb[j]);
        vl[j] = *(const bf16x8*)(slo + gb[j]);
    }

    for (int k0 = 0; k0 < kchunk; k0 += BK) {
        __syncthreads();                       // prior compute done before LDS overwrite
        #pragma unroll
        for (int j = 0; j < 4; ++j) {
            *(bf16x8*)&As[lofs[j]] = va[j];
            *(bf16x8*)&Bh[lofs[j]] = vh[j];
            *(bf16x8*)&Bl[lofs[j]] = vl[j];
        }
        // issue next iteration's global loads; latency hides under compute below
        {
            int kn = k0 + BK;
            int ks = (kn < kchunk) ? kn : 0;   // last iter: dummy reload of k=0 (no OOB)
            #pragma unroll
            for (int j = 0; j < 4; ++j) {
                va[j] = *(const bf16x8*)(xb  + ga[j] + ks);
                vh[j] = *(const bf16x8*)(shi + gb[j] + ks);
                vl[j] = *(const bf16x8*)(slo + gb[j] + ks);
            }
        }
        __syncthreads();                       // LDS tiles visible to both waves
        #pragma unroll
        for (int kk = 0; kk < BK; kk += 32) {
            const int gr = (kk >> 3) + quad;
            bf16x8 a[4];
            #pragma unroll
            for (int mt = 0; mt < 4; ++mt)
                a[mt] = *(const bf16x8*)&As[(mt * 16 + ln) * LSTRIDE + gr * 8];
            #pragma unroll
            for (int ct = 0; ct < 2; ++ct) {
                int rb = w * 32 + ct * 16 + ln;
                bf16x8 bh = *(const bf16x8*)&Bh[rb * LSTRIDE + gr * 8];
                bf16x8 bl = *(const bf16x8*)&Bl[rb * LSTRIDE + gr * 8];
                #pragma unroll
                for (int mt = 0; mt < 4; ++mt) {
                    acc[mt][ct] = __builtin_amdgcn_mfma_f32_16x16x32_bf16(a[mt], bh, acc[mt][ct], 0, 0, 0);
                    acc[mt][ct] = __builtin_amdgcn_mfma_f32_16x16x32_bf16(a[mt], bl, acc[mt][ct], 0, 0, 0);
                }
            }
        }
    }
    float* prow = part + (size_t)blockIdx.z * (Bsz * Dd);
    #pragma unroll
    for (int mt = 0; mt < 4; ++mt)
        #pragma unroll
        for (int ct = 0; ct < 2; ++ct)
            #pragma unroll
            for (int rr = 0; rr < 4; ++rr) {
                int m = m0 + mt * 16 + quad * 4 + rr;
                int n = n0 + w * 32 + ct * 16 + ln;
                prow[(size_t)m * Dd + n] = acc[mt][ct][rr];
            }
}

// ---------------- block reduction helpers (256 threads = 4 waves) ----------------
__device__ __forceinline__ float block_max256(float v, float* redf) {
    #pragma unroll
    for (int off = 32; off; off >>= 1) v = fmaxf(v, __shfl_down(v, off));
    __syncthreads();
    if ((threadIdx.x & 63) == 0) redf[threadIdx.x >> 6] = v;
    __syncthreads();
    return fmaxf(fmaxf(redf[0], redf[1]), fmaxf(redf[2], redf[3]));
}
__device__ __forceinline__ float block_sum256(float v, float* redf) {
    #pragma unroll
    for (int off = 32; off; off >>= 1) v += __shfl_down(v, off);
    __syncthreads();
    if ((threadIdx.x & 63) == 0) redf[threadIdx.x >> 6] = v;
    __syncthreads();
    return (redf[0] + redf[1]) + (redf[2] + redf[3]);    // fixed order: deterministic
}

// ---- Kernel 3: per-row epilogue; register-cached top-k + algebraic lse_y ----
__global__ __launch_bounds__(256) void k_epilogue(const float* __restrict__ x,
                                                  const float* __restrict__ W,
                                                  const int* __restrict__ radius_raw,
                                                  const float* __restrict__ gu,
                                                  const float* __restrict__ uvec,
                                                  const float* __restrict__ part,
                                                  const float* __restrict__ bias,
                                                  float* __restrict__ out,
                                                  int nsplit) {
    __shared__ float scx_s[Dd];        // 16 KB: sc values for flip-position lookups
    __shared__ float redf[2][4];       // double-buffered argmax combine
    __shared__ int   redi[2][4];
    __shared__ float redsum[4];
    __shared__ int   flips[MAXR];

    const int b = blockIdx.x;
    const int tid = threadIdx.x;
    const float* xrow  = x  + (size_t)b * Dd;
    const float* gurow = gu + (size_t)b * Dd;

    // ---- phase 1: grad = sum_z part[z] + bias (fixed order); sc/key in registers ----
    float4 g4[4], bs4[4], xv4[4], uu4[4];
    #pragma unroll
    for (int c = 0; c < 4; ++c) {
        int j = c * 1024 + tid * 4;
        g4[c]  = *(const float4*)(part + (size_t)b * Dd + j);      // z = 0
        bs4[c] = *(const float4*)(bias + j);
        xv4[c] = *(const float4*)(xrow + j);
        uu4[c] = *(const float4*)(gurow + j);
    }
    for (int z = 1; z < nsplit; ++z) {
        const float* pz = part + (size_t)z * (Bsz * Dd) + (size_t)b * Dd;
        #pragma unroll
        for (int c = 0; c < 4; ++c) {
            float4 a = *(const float4*)(pz + c * 1024 + tid * 4);
            g4[c].x += a.x; g4[c].y += a.y; g4[c].z += a.z; g4[c].w += a.w;
        }
    }
    float sc[16], ky[16];
    float lmax = -FMAX;
    float lkey = -FMAX; int lidx = 0x7fffffff;
    #pragma unroll
    for (int c = 0; c < 4; ++c) {
        const float* gg = (const float*)&g4[c];
        const float* gc = (const float*)&bs4[c];
        const float* gx = (const float*)&xv4[c];
        const float* gup = (const float*)&uu4[c];
        #pragma unroll
        for (int e = 0; e < 4; ++e) {
            int r = c * 4 + e;
            float g = gg[e] + gc[e];
            float s = (1.0f - 2.0f * gx[e]) * g * 0.5f;
            float k = s - logf(-logf(fmaxf(gup[e], 1e-10f)));
            sc[r] = s;
            ky[r] = k;
            lmax = fmaxf(lmax, s);
            if (k > lkey) { lkey = k; lidx = c * 1024 + tid * 4 + e; }  // incr j: lowest-idx tie
        }
        *(float4*)&scx_s[c * 1024 + tid * 4] = *(const float4*)&sc[c * 4];
    }

    // ---- lse_x ----
    float mx = block_max256(lmax, redsum);
    float ls = 0.0f;
    #pragma unroll
    for (int r = 0; r < 16; ++r) ls += expf(sc[r] - mx);
    float sum_x = block_sum256(ls, redsum);
    float lse_x = mx + logf(sum_x);

    // ---- top-radius: tournament over register-cached per-thread maxima ----
    const int radius = radius_raw[b] + 1;             // [1, 15]
    unsigned removed = 0;
    for (int t = 0; t < radius; ++t) {
        float v = lkey; int idx = lidx;
        #pragma unroll
        for (int off = 32; off; off >>= 1) {
            float v2 = __shfl_down(v, off);
            int   i2 = __shfl_down(idx, off);
            if (v2 > v || (v2 == v && i2 < idx)) { v = v2; idx = i2; }
        }
        const int buf = t & 1;
        if ((tid & 63) == 0) { redf[buf][tid >> 6] = v; redi[buf][tid >> 6] = idx; }
        __syncthreads();
        float bv = redf[buf][0]; int bi = redi[buf][0];
        #pragma unroll
        for (int w2 = 1; w2 < 4; ++w2) {
            float v2 = redf[buf][w2]; int i2 = redi[buf][w2];
            if (v2 > bv || (v2 == bv && i2 < bi)) { bv = v2; bi = i2; }
        }
        if (tid == ((bi >> 2) & 255)) {       // owner: remove + rescan registers
            removed |= 1u << (((bi >> 10) << 2) | (bi & 3));
            lkey = -FMAX; lidx = 0x7fffffff;
            #pragma unroll
            for (int c = 0; c < 4; ++c)
                #pragma unroll
                for (int e = 0; e < 4; ++e) {
                    int r = c * 4 + e;
                    if (!(removed & (1u << r)) && ky[r] > lkey) {
                        lkey = ky[r]; lidx = c * 1024 + tid * 4 + e;
                    }
                }
        }
        if (tid == 0) flips[t] = bi;
    }
    __syncthreads();                           // flips[] visible to all

    // ---- lse_y via correction: sum_y = sum_x + sum_flips(e^{-sc-mx} - e^{+sc-mx}) ----
    float delta = 0.0f;
    if (tid < radius) {
        float sv = scx_s[flips[tid]];
        delta = expf(-sv - mx) - expf(sv - mx);
    }
    float sum_y = sum_x + block_sum256(delta, redsum);
    float lse_y = mx + logf(sum_y);

    // ---- pair term: 0.25 * sum_{p,q in flips} d_p d_q (W_pq + W_qp) ----
    float ts = 0.0f;
    for (int t = tid; t < radius * radius; t += 256) {
        int p = flips[t / radius], q = flips[t % radius];
        float dp = 1.0f - 2.0f * xrow[p];
        float dq = 1.0f - 2.0f * xrow[q];
        ts += 0.25f * dp * dq * (W[(size_t)p * Dd + q] + W[(size_t)q * Dd + p]);
    }
    float T = block_sum256(ts, redsum);

    float log_acc = fminf(T + lse_x - lse_y, 0.0f);
    int accepted = (expf(log_acc) > uvec[b]) ? 1 : 0;

    // ---- output: x everywhere (from registers), flips overwritten iff accepted ----
    float* orow = out + (size_t)b * Dd;
    #pragma unroll
    for (int c = 0; c < 4; ++c)
        *(float4*)(orow + c * 1024 + tid * 4) = xv4[c];
    __syncthreads();
    if (accepted && tid < radius) {
        int p = flips[tid];
        orow[p] = 1.0f - xrow[p];
    }
}

extern "C" void kernel_launch(void* const* d_in, const int* in_sizes, int n_in,
                              void* d_out, int out_size, void* d_ws, size_t ws_size,
                              hipStream_t stream) {
    const float* x          = (const float*)d_in[0];
    const float* W          = (const float*)d_in[1];
    const float* bias       = (const float*)d_in[2];
    const int*   radius_raw = (const int*)d_in[3];
    const float* gu         = (const float*)d_in[4];
    const float* u          = (const float*)d_in[5];
    float* out = (float*)d_out;

    // ws: shi 33.55 MB | slo 33.55 MB | xb 2.1 MB | part nsplit*4.19 MB
    unsigned short* shi = (unsigned short*)d_ws;
    unsigned short* slo = shi + (size_t)Dd * Dd;
    unsigned short* xb  = slo + (size_t)Dd * Dd;
    float*          prt = (float*)(xb + (size_t)Bsz * Dd);

    // nsplit=4 needs 85,983,232 B; proven-fit fallback (77,594,624 B) is nsplit=2.
    // ws_size is constant across calls => same work every call (graph-safe).
    const size_t fixed = (size_t)2 * Dd * Dd * 2 + (size_t)Bsz * Dd * 2;
    const int nsplit = (ws_size >= fixed + (size_t)4 * Bsz * Dd * 4) ? 4 : 2;
    const int kchunk = Dd / nsplit;

    k_ssym<<<2080, 256, 0, stream>>>(W, x, shi, slo, xb);
    k_gemm<<<dim3(64, 4, nsplit), 128, 0, stream>>>(xb, shi, slo, prt, kchunk);
    k_epilogue<<<Bsz, 256, 0, stream>>>(x, W, radius_raw, gu, u, prt, bias, out, nsplit);
}